// Round 1
// baseline (3157.941 us; speedup 1.0000x reference)
//
#include <hip/hip_runtime.h>
#include <math.h>

#define D 256
#define H 4
#define A 32
#define P 4
#define HA 128
#define RHID 64
#define ROWS 64
#define SXS 260   // padded stride for s_x (64*260*4 = 66560 B, 16B-aligned rows)
#define SQS 132   // padded stride for s_q (64*132*4 = 33792 B, 16B-aligned rows)
#define SCALE_F 0.17677669529663687f

__global__ __launch_bounds__(256)
void faiia_kernel(const float* __restrict__ x, const float* __restrict__ mp,
    const float* __restrict__ Wq, const float* __restrict__ bq,
    const float* __restrict__ pk, const float* __restrict__ pv,
    const float* __restrict__ imp, const float* __restrict__ fa,
    const float* __restrict__ ft, const float* __restrict__ Wo,
    const float* __restrict__ bo, const float* __restrict__ lng,
    const float* __restrict__ lnb, const float* __restrict__ Wf,
    const float* __restrict__ bf, const float* __restrict__ Wg1,
    const float* __restrict__ bg1, const float* __restrict__ Wg2,
    const float* __restrict__ bg2, const float* __restrict__ lnFg,
    const float* __restrict__ lnFb, float* __restrict__ out)
{
  __shared__ __attribute__((aligned(16))) float s_x[ROWS*SXS];  // x tile, later out_pre, later gated+residual
  __shared__ __attribute__((aligned(16))) float s_q[ROWS*SQS];  // q, then combined, then hidden
  __shared__ float s_pk[H*P*A], s_pv[H*P*A], s_imp[H*P], s_fa[H], s_ft[H];
  __shared__ float s_Wo[H*1025];   // head stride 1025 to break bank aliasing
  __shared__ float s_bq[HA], s_bo[HA], s_lng[HA], s_lnb[HA];
  __shared__ float s_bf[D], s_bg1[RHID], s_bg2[D], s_lnFg[D], s_lnFb[D];

  const int t = threadIdx.x;
  const int lane = t & 63;
  const int wid = t >> 6;
  const int row0 = blockIdx.x * ROWS;

  // ---- stage small constants ----
  for (int i = t; i < H*P*A; i += 256) { s_pk[i] = pk[i]; s_pv[i] = pv[i]; }
  if (t < H*P) s_imp[t] = imp[t];
  if (t < H) { s_fa[t] = fa[t]; s_ft[t] = ft[t]; }
  for (int i = t; i < H*A*A; i += 256) s_Wo[(i >> 10)*1025 + (i & 1023)] = Wo[i];
  if (t < HA) { s_bq[t] = bq[t]; s_bo[t] = bo[t]; s_lng[t] = lng[t]; s_lnb[t] = lnb[t]; }
  s_bf[t] = bf[t]; s_bg2[t] = bg2[t]; s_lnFg[t] = lnFg[t]; s_lnFb[t] = lnFb[t];
  if (t < RHID) s_bg1[t] = bg1[t];

  // ---- stage x tile (coalesced float4) ----
  {
    const float4* xg = reinterpret_cast<const float4*>(x + (size_t)row0 * D);
    #pragma unroll
    for (int i = 0; i < 16; ++i) {
      int f = t + 256*i;            // 0..4095 float4s
      int r = f >> 6, c4 = f & 63;  // 64 float4 per row
      float4 v = xg[f];
      *reinterpret_cast<float4*>(&s_x[r*SXS + c4*4]) = v;
    }
  }
  __syncthreads();

  // ---- Phase A: q[r][h*32+a] = x[r,:] . Wq[h,:,a] + bq  (wave = head) ----
  {
    const int h = wid;
    const int a_ = lane & 31;
    const int rh = lane >> 5;       // row half: 0 -> rows 0..31, 1 -> rows 32..63
    float acc[32];
    #pragma unroll
    for (int i = 0; i < 32; ++i) acc[i] = 0.f;
    const float* wqp = Wq + h*(D*A) + a_;
    #pragma unroll 2
    for (int d4 = 0; d4 < 64; ++d4) {
      float w0 = wqp[(4*d4+0)*A];
      float w1 = wqp[(4*d4+1)*A];
      float w2 = wqp[(4*d4+2)*A];
      float w3 = wqp[(4*d4+3)*A];
      #pragma unroll
      for (int rr = 0; rr < 32; ++rr) {
        float4 xv = *reinterpret_cast<const float4*>(&s_x[(rh*32+rr)*SXS + 4*d4]);
        acc[rr] = fmaf(xv.x, w0, acc[rr]);
        acc[rr] = fmaf(xv.y, w1, acc[rr]);
        acc[rr] = fmaf(xv.z, w2, acc[rr]);
        acc[rr] = fmaf(xv.w, w3, acc[rr]);
      }
    }
    const float bias = s_bq[h*A + a_];
    #pragma unroll
    for (int rr = 0; rr < 32; ++rr)
      s_q[(rh*32+rr)*SQS + h*A + a_] = acc[rr] + bias;
  }
  __syncthreads();

  // ---- Phase B: prototype attention + Wo + per-head LN (thread = (row, head)) ----
  {
    const int r = t >> 2;
    const int h = t & 3;
    float q[32];
    #pragma unroll
    for (int a = 0; a < 32; ++a) q[a] = s_q[r*SQS + h*A + a];
    const float mpv = mp[row0 + r];
    const float u = 1.f - 2.f*fabsf(mpv - 0.5f);
    const float up = u + 1e-8f;
    const float fw = s_fa[h] * up * up * s_ft[h];   // GAMMA = 2.0
    const float mod = 1.f + fw;
    float sc[4];
    #pragma unroll
    for (int p = 0; p < 4; ++p) {
      float s = s_imp[h*P + p];
      #pragma unroll
      for (int a = 0; a < 32; ++a) s = fmaf(q[a], s_pk[(h*P + p)*A + a], s);
      sc[p] = s * mod * SCALE_F;
    }
    float mx = fmaxf(fmaxf(sc[0], sc[1]), fmaxf(sc[2], sc[3]));
    float e0 = expf(sc[0]-mx), e1 = expf(sc[1]-mx), e2 = expf(sc[2]-mx), e3 = expf(sc[3]-mx);
    float inv = 1.f / (e0+e1+e2+e3);
    e0 *= inv; e1 *= inv; e2 *= inv; e3 *= inv;
    float att[32];
    #pragma unroll
    for (int a = 0; a < 32; ++a) {
      att[a] = e0*s_pv[(h*P+0)*A + a] + e1*s_pv[(h*P+1)*A + a]
             + e2*s_pv[(h*P+2)*A + a] + e3*s_pv[(h*P+3)*A + a];
    }
    float ho[32];
    float sum = 0.f;
    #pragma unroll
    for (int o = 0; o < 32; ++o) {
      float s = s_bo[h*A + o];
      #pragma unroll
      for (int a = 0; a < 32; ++a) s = fmaf(att[a], s_Wo[h*1025 + a*A + o], s);
      ho[o] = s; sum += s;
    }
    float mean = sum * (1.f/32.f);
    float vs = 0.f;
    #pragma unroll
    for (int o = 0; o < 32; ++o) { float dv = ho[o]-mean; vs = fmaf(dv, dv, vs); }
    float rstd = rsqrtf(vs*(1.f/32.f) + 1e-5f);
    #pragma unroll
    for (int o = 0; o < 32; ++o)
      s_q[r*SQS + h*A + o] = (ho[o]-mean)*rstd*s_lng[h*A+o] + s_lnb[h*A+o];
  }
  __syncthreads();

  // ---- Phase C: out_pre = combined @ Wf + bf  (wave owns 64 cols, all 64 rows) ----
  {
    const int c = wid*64 + lane;
    float acc[64];
    #pragma unroll
    for (int i = 0; i < 64; ++i) acc[i] = 0.f;
    const float* wfp = Wf + c;
    for (int k4 = 0; k4 < 32; ++k4) {
      float w0 = wfp[(4*k4+0)*D];
      float w1 = wfp[(4*k4+1)*D];
      float w2 = wfp[(4*k4+2)*D];
      float w3 = wfp[(4*k4+3)*D];
      #pragma unroll
      for (int r = 0; r < 64; ++r) {
        float4 cv = *reinterpret_cast<const float4*>(&s_q[r*SQS + 4*k4]);
        acc[r] = fmaf(cv.x, w0, acc[r]);
        acc[r] = fmaf(cv.y, w1, acc[r]);
        acc[r] = fmaf(cv.z, w2, acc[r]);
        acc[r] = fmaf(cv.w, w3, acc[r]);
      }
    }
    const float bfv = s_bf[c];
    #pragma unroll
    for (int r = 0; r < 64; ++r)
      s_x[r*SXS + c] = acc[r] + bfv;
  }
  __syncthreads();

  // ---- Phase D1: hidden = relu([out_pre, difficulty] @ Wg1 + bg1)  (wave = 16 rows, lane = col) ----
  {
    const int rbase = wid*16;
    float acc[16];
    #pragma unroll
    for (int i = 0; i < 16; ++i) acc[i] = 0.f;
    for (int i4 = 0; i4 < 64; ++i4) {
      float w0 = Wg1[(4*i4+0)*RHID + lane];
      float w1 = Wg1[(4*i4+1)*RHID + lane];
      float w2 = Wg1[(4*i4+2)*RHID + lane];
      float w3 = Wg1[(4*i4+3)*RHID + lane];
      #pragma unroll
      for (int rr = 0; rr < 16; ++rr) {
        float4 ov = *reinterpret_cast<const float4*>(&s_x[(rbase+rr)*SXS + 4*i4]);
        acc[rr] = fmaf(ov.x, w0, acc[rr]);
        acc[rr] = fmaf(ov.y, w1, acc[rr]);
        acc[rr] = fmaf(ov.z, w2, acc[rr]);
        acc[rr] = fmaf(ov.w, w3, acc[rr]);
      }
    }
    const float wg1d = Wg1[256*RHID + lane];
    const float b1 = s_bg1[lane];
    #pragma unroll
    for (int rr = 0; rr < 16; ++rr) {
      float mpv = mp[row0 + rbase + rr];
      float diff = 1.f - 2.f*fabsf(mpv - 0.5f);
      float hv = fmaf(diff, wg1d, acc[rr] + b1);
      s_q[(rbase+rr)*SQS + lane] = fmaxf(hv, 0.f);
    }
  }
  __syncthreads();

  // ---- Phase D2: gate = sigmoid(hidden @ Wg2 + bg2); val = out_pre*gate + x ----
  {
    const int c = wid*64 + lane;
    float acc[64];
    #pragma unroll
    for (int i = 0; i < 64; ++i) acc[i] = 0.f;
    for (int j4 = 0; j4 < 16; ++j4) {
      float w0 = Wg2[(4*j4+0)*D + c];
      float w1 = Wg2[(4*j4+1)*D + c];
      float w2 = Wg2[(4*j4+2)*D + c];
      float w3 = Wg2[(4*j4+3)*D + c];
      #pragma unroll
      for (int r = 0; r < 64; ++r) {
        float4 hv = *reinterpret_cast<const float4*>(&s_q[r*SQS + 4*j4]);
        acc[r] = fmaf(hv.x, w0, acc[r]);
        acc[r] = fmaf(hv.y, w1, acc[r]);
        acc[r] = fmaf(hv.z, w2, acc[r]);
        acc[r] = fmaf(hv.w, w3, acc[r]);
      }
    }
    const float b2 = s_bg2[c];
    const float* xg2 = x + (size_t)row0 * D + c;
    #pragma unroll 4
    for (int r = 0; r < 64; ++r) {
      float logit = acc[r] + b2;
      float gate = 1.f / (1.f + expf(-logit));
      float val = fmaf(s_x[r*SXS + c], gate, 0.f) + xg2[(size_t)r*D];
      s_x[r*SXS + c] = val;
    }
  }
  __syncthreads();

  // ---- Phase E: final LN over D=256, coalesced store ----
  {
    const int rbase = wid*16;
    for (int rr = 0; rr < 16; ++rr) {
      const int r = rbase + rr;
      float v0 = s_x[r*SXS + lane];
      float v1 = s_x[r*SXS + 64 + lane];
      float v2 = s_x[r*SXS + 128 + lane];
      float v3 = s_x[r*SXS + 192 + lane];
      float s  = v0+v1+v2+v3;
      float sq = v0*v0+v1*v1+v2*v2+v3*v3;
      #pragma unroll
      for (int m = 1; m < 64; m <<= 1) {
        s  += __shfl_xor(s, m, 64);
        sq += __shfl_xor(sq, m, 64);
      }
      float mean = s * (1.f/256.f);
      float var  = sq * (1.f/256.f) - mean*mean;
      float rstd = rsqrtf(var + 1e-5f);
      float* op = out + (size_t)(row0 + r) * D;
      op[lane]       = (v0-mean)*rstd*s_lnFg[lane]       + s_lnFb[lane];
      op[64 + lane]  = (v1-mean)*rstd*s_lnFg[64 + lane]  + s_lnFb[64 + lane];
      op[128 + lane] = (v2-mean)*rstd*s_lnFg[128 + lane] + s_lnFb[128 + lane];
      op[192 + lane] = (v3-mean)*rstd*s_lnFg[192 + lane] + s_lnFb[192 + lane];
    }
  }
}

extern "C" void kernel_launch(void* const* d_in, const int* in_sizes, int n_in,
                              void* d_out, int out_size, void* d_ws, size_t ws_size,
                              hipStream_t stream) {
  (void)in_sizes; (void)n_in; (void)d_ws; (void)ws_size; (void)out_size;
  const float* x   = (const float*)d_in[0];
  const float* mp  = (const float*)d_in[1];
  const float* Wq  = (const float*)d_in[2];
  const float* bq  = (const float*)d_in[3];
  const float* pk  = (const float*)d_in[4];
  const float* pv  = (const float*)d_in[5];
  const float* imp = (const float*)d_in[6];
  const float* fa  = (const float*)d_in[7];
  const float* ft  = (const float*)d_in[8];
  const float* Wo  = (const float*)d_in[9];
  const float* bo  = (const float*)d_in[10];
  const float* lng = (const float*)d_in[11];
  const float* lnb = (const float*)d_in[12];
  const float* Wf  = (const float*)d_in[13];
  const float* bf  = (const float*)d_in[14];
  const float* Wg1 = (const float*)d_in[15];
  const float* bg1 = (const float*)d_in[16];
  const float* Wg2 = (const float*)d_in[17];
  const float* bg2 = (const float*)d_in[18];
  const float* lnFg= (const float*)d_in[19];
  const float* lnFb= (const float*)d_in[20];
  float* out = (float*)d_out;

  dim3 grid(262144 / ROWS);
  dim3 block(256);
  hipLaunchKernelGGL(faiia_kernel, grid, block, 0, stream,
                     x, mp, Wq, bq, pk, pv, imp, fa, ft, Wo, bo, lng, lnb,
                     Wf, bf, Wg1, bg1, Wg2, bg2, lnFg, lnFb, out);
}

// Round 2
// 262.617 us; speedup vs baseline: 12.0249x; 12.0249x over previous
//
#include <hip/hip_runtime.h>
#include <math.h>

typedef __bf16 bf16;
typedef __bf16 bf16x8 __attribute__((ext_vector_type(8)));
typedef float f32x4 __attribute__((ext_vector_type(4)));

#define MFMA16(a,b,c) __builtin_amdgcn_mfma_f32_16x16x32_bf16((a),(b),(c),0,0,0)

#define D 256
#define H 4
#define A 32
#define P 4
#define HA 128
#define RHID 64
#define ROWS 64
#define NROWS_TOT 262144
#define SQP 136               // padded q row stride (bf16), multiple of 8
#define SCALE_F 0.17677669529663687f

// ws offsets in bf16 elements
#define OFF_Q  0
#define OFF_F  32768
#define OFF_G1 65536
#define OFF_G2 81920
#define OFF_O  98304
#define NPACK  102400

// ---------------- weight prepack: f32 -> bf16 in MFMA B-fragment order ----------------
// B-fragment for 16x16x32: lane l holds col n = l&15, k = (l>>4)*8 + j (j=0..7, contiguous)
__global__ __launch_bounds__(256)
void prep_kernel(const float* __restrict__ Wq, const float* __restrict__ Wf,
                 const float* __restrict__ Wg1, const float* __restrict__ Wg2,
                 const float* __restrict__ Wo, bf16* __restrict__ ws)
{
  int i = blockIdx.x * 256 + threadIdx.x;
  if (i >= NPACK) return;
  float v;
  if (i < OFF_F) {              // packQ [h(4)][ks(8)][nt(2)][l(64)][j(8)], K=256,N=32 per head
    int j = i & 7, l = (i >> 3) & 63, nt = (i >> 9) & 1, ks = (i >> 10) & 7, h = i >> 13;
    int k = ks * 32 + (l >> 4) * 8 + j, n = nt * 16 + (l & 15);
    v = Wq[(h * 256 + k) * 32 + n];
  } else if (i < OFF_G1) {      // packF [ks(4)][gnt(16)][l][j], K=128,N=256
    int ii = i - OFF_F;
    int j = ii & 7, l = (ii >> 3) & 63, g = (ii >> 9) & 15, ks = ii >> 13;
    int k = ks * 32 + (l >> 4) * 8 + j, n = g * 16 + (l & 15);
    v = Wf[k * 256 + n];
  } else if (i < OFF_G2) {      // packG1 [ks(8)][nt(4)][l][j], K=256,N=64 (row 256 handled separately)
    int ii = i - OFF_G1;
    int j = ii & 7, l = (ii >> 3) & 63, nt = (ii >> 9) & 3, ks = ii >> 11;
    int k = ks * 32 + (l >> 4) * 8 + j, n = nt * 16 + (l & 15);
    v = Wg1[k * 64 + n];
  } else if (i < OFF_O) {       // packG2 [ks(2)][gnt(16)][l][j], K=64,N=256
    int ii = i - OFF_G2;
    int j = ii & 7, l = (ii >> 3) & 63, g = (ii >> 9) & 15, ks = ii >> 13;
    int k = ks * 32 + (l >> 4) * 8 + j, n = g * 16 + (l & 15);
    v = Wg2[k * 256 + n];
  } else {                      // packO [h(4)][nt(2)][l][j], K=32,N=32 per head
    int ii = i - OFF_O;
    int j = ii & 7, l = (ii >> 3) & 63, nt = (ii >> 9) & 1, h = ii >> 10;
    int k = (l >> 4) * 8 + j, n = nt * 16 + (l & 15);
    v = Wo[(h * 32 + k) * 32 + n];
  }
  ws[i] = (bf16)v;
}

// ---------------- fused main kernel: 64 rows/block, 4 waves, 5 MFMA GEMMs ----------------
__global__ __launch_bounds__(256, 2)
void faiia_kernel(const float* __restrict__ x, const float* __restrict__ mp,
    const float* __restrict__ bq, const float* __restrict__ pk,
    const float* __restrict__ pv, const float* __restrict__ imp,
    const float* __restrict__ fa, const float* __restrict__ ft,
    const float* __restrict__ bo, const float* __restrict__ lng,
    const float* __restrict__ lnb, const float* __restrict__ bfb,
    const float* __restrict__ Wg1, const float* __restrict__ bg1,
    const float* __restrict__ bg2, const float* __restrict__ lnFg,
    const float* __restrict__ lnFb, const bf16* __restrict__ ws,
    float* __restrict__ out)
{
  // region A (32KB): xfrag [mt4][ks8][64][8] -> attfrag [h4][mt4][64][8] (lower 16KB)
  //                  + combfrag [ks2:4][mt4][64][8] (upper 16KB) -> opfrag [ks3:8][mt4][64][8]
  __shared__ __attribute__((aligned(16))) bf16 s_regA[16384];
  __shared__ __attribute__((aligned(16))) bf16 s_q[ROWS * SQP];      // q bf16 row-major
  __shared__ __attribute__((aligned(16))) bf16 s_hfrag[4096];        // hidden frag [ks2][mt4][64][8]
  __shared__ float s_pk[H*P*A], s_pv[H*P*A], s_imp[H*P], s_fa[H], s_ft[H];
  __shared__ float s_bq[HA], s_bo[HA], s_lng[HA], s_lnb[HA];
  __shared__ float s_bf[D], s_bg1[RHID], s_wg1d[RHID], s_bg2[D], s_lnFg[D], s_lnFb[D];
  __shared__ float s_diff[ROWS];
  __shared__ float s_lnsum[ROWS*4], s_lnsq[ROWS*4], s_rmean[ROWS], s_rrstd[ROWS];

  const int t = threadIdx.x;
  const int lane = t & 63;
  const int w = t >> 6;           // wave id
  const int lr = lane >> 4;       // row-group 0..3
  const int lc = lane & 15;       // col-in-tile
  const int row0 = blockIdx.x * ROWS;

  // ---- stage small constants ----
  for (int i = t; i < H*P*A; i += 256) { s_pk[i] = pk[i]; s_pv[i] = pv[i]; }
  if (t < H*P) s_imp[t] = imp[t];
  if (t < H) { s_fa[t] = fa[t]; s_ft[t] = ft[t]; }
  if (t < HA) { s_bq[t] = bq[t]; s_bo[t] = bo[t]; s_lng[t] = lng[t]; s_lnb[t] = lnb[t]; }
  s_bf[t] = bfb[t]; s_bg2[t] = bg2[t]; s_lnFg[t] = lnFg[t]; s_lnFb[t] = lnFb[t];
  if (t < RHID) { s_bg1[t] = bg1[t]; s_wg1d[t] = Wg1[256*RHID + t]; }
  if (t < ROWS) { float m = mp[row0 + t]; s_diff[t] = 1.f - 2.f*fabsf(m - 0.5f); }

  // ---- stage x -> bf16 A-fragments: slot s = (mt*8+ks)*64 + l ----
  {
    const float* xbase = x + (size_t)row0 * D;
    #pragma unroll
    for (int i = 0; i < 8; ++i) {
      int s = t + 256*i;
      int l = s & 63, ks = (s >> 6) & 7, mt = s >> 9;
      int row = mt*16 + (l & 15);
      int k0 = ks*32 + ((l >> 4) & 3)*8;
      const float* xp = xbase + row*D + k0;
      float4 v0 = *reinterpret_cast<const float4*>(xp);
      float4 v1 = *reinterpret_cast<const float4*>(xp + 4);
      bf16x8 fr;
      fr[0]=(bf16)v0.x; fr[1]=(bf16)v0.y; fr[2]=(bf16)v0.z; fr[3]=(bf16)v0.w;
      fr[4]=(bf16)v1.x; fr[5]=(bf16)v1.y; fr[6]=(bf16)v1.z; fr[7]=(bf16)v1.w;
      *reinterpret_cast<bf16x8*>(&s_regA[(size_t)s * 8]) = fr;
    }
  }
  __syncthreads();

  // ---- GEMM1: Q = X(64x256) * Wq[head=w](256x32); wave w computes head w ----
  {
    f32x4 acc[4][2];
    #pragma unroll
    for (int mt = 0; mt < 4; ++mt) { acc[mt][0] = (f32x4)0.f; acc[mt][1] = (f32x4)0.f; }
    const bf16x8* pQ = reinterpret_cast<const bf16x8*>(ws + OFF_Q);
    #pragma unroll
    for (int ks = 0; ks < 8; ++ks) {
      bf16x8 b0 = pQ[((w*8 + ks)*2 + 0)*64 + lane];
      bf16x8 b1 = pQ[((w*8 + ks)*2 + 1)*64 + lane];
      #pragma unroll
      for (int mt = 0; mt < 4; ++mt) {
        bf16x8 a = *reinterpret_cast<const bf16x8*>(&s_regA[((mt*8 + ks)*64 + lane)*8]);
        acc[mt][0] = MFMA16(a, b0, acc[mt][0]);
        acc[mt][1] = MFMA16(a, b1, acc[mt][1]);
      }
    }
    float bq0 = s_bq[w*32 + lc], bq1 = s_bq[w*32 + 16 + lc];
    #pragma unroll
    for (int mt = 0; mt < 4; ++mt)
      #pragma unroll
      for (int r = 0; r < 4; ++r) {
        int row = mt*16 + lr*4 + r;
        s_q[row*SQP + w*32 + lc]      = (bf16)(acc[mt][0][r] + bq0);
        s_q[row*SQP + w*32 + 16 + lc] = (bf16)(acc[mt][1][r] + bq1);
      }
  }
  __syncthreads();

  // ---- Phase B: prototype attention, thread = (row, head); writes attfrag (bf16) ----
  {
    const int r = t >> 2, h = t & 3;
    float q[32];
    #pragma unroll
    for (int g = 0; g < 4; ++g) {
      bf16x8 v = *reinterpret_cast<const bf16x8*>(&s_q[r*SQP + h*32 + g*8]);
      #pragma unroll
      for (int j = 0; j < 8; ++j) q[g*8 + j] = (float)v[j];
    }
    float u = s_diff[r];
    float up = u + 1e-8f;
    float mod = 1.f + s_fa[h]*up*up*s_ft[h];
    float sc[4];
    #pragma unroll
    for (int p = 0; p < 4; ++p) {
      float s = s_imp[h*4 + p];
      const float4* kp = reinterpret_cast<const float4*>(&s_pk[(h*4 + p)*32]);
      #pragma unroll
      for (int g = 0; g < 8; ++g) {
        float4 kv = kp[g];
        s = fmaf(q[g*4+0], kv.x, s); s = fmaf(q[g*4+1], kv.y, s);
        s = fmaf(q[g*4+2], kv.z, s); s = fmaf(q[g*4+3], kv.w, s);
      }
      sc[p] = s * mod * SCALE_F;
    }
    float mx = fmaxf(fmaxf(sc[0], sc[1]), fmaxf(sc[2], sc[3]));
    float e0 = expf(sc[0]-mx), e1 = expf(sc[1]-mx), e2 = expf(sc[2]-mx), e3 = expf(sc[3]-mx);
    float inv = 1.f / (e0+e1+e2+e3);
    e0 *= inv; e1 *= inv; e2 *= inv; e3 *= inv;
    const float4* p0 = reinterpret_cast<const float4*>(&s_pv[(h*4+0)*32]);
    const float4* p1 = reinterpret_cast<const float4*>(&s_pv[(h*4+1)*32]);
    const float4* p2 = reinterpret_cast<const float4*>(&s_pv[(h*4+2)*32]);
    const float4* p3 = reinterpret_cast<const float4*>(&s_pv[(h*4+3)*32]);
    const int mt = r >> 4, rl = r & 15;
    #pragma unroll
    for (int g = 0; g < 4; ++g) {
      float4 a0 = p0[g*2],   b0v = p0[g*2+1];
      float4 a1 = p1[g*2],   b1v = p1[g*2+1];
      float4 a2 = p2[g*2],   b2v = p2[g*2+1];
      float4 a3 = p3[g*2],   b3v = p3[g*2+1];
      bf16x8 av;
      av[0] = (bf16)(e0*a0.x + e1*a1.x + e2*a2.x + e3*a3.x);
      av[1] = (bf16)(e0*a0.y + e1*a1.y + e2*a2.y + e3*a3.y);
      av[2] = (bf16)(e0*a0.z + e1*a1.z + e2*a2.z + e3*a3.z);
      av[3] = (bf16)(e0*a0.w + e1*a1.w + e2*a2.w + e3*a3.w);
      av[4] = (bf16)(e0*b0v.x + e1*b1v.x + e2*b2v.x + e3*b3v.x);
      av[5] = (bf16)(e0*b0v.y + e1*b1v.y + e2*b2v.y + e3*b3v.y);
      av[6] = (bf16)(e0*b0v.z + e1*b1v.z + e2*b2v.z + e3*b3v.z);
      av[7] = (bf16)(e0*b0v.w + e1*b1v.w + e2*b2v.w + e3*b3v.w);
      // attfrag[h][mt][lane' = g*16 + rl][j]
      *reinterpret_cast<bf16x8*>(&s_regA[(((h*4) + mt)*64 + g*16 + rl)*8]) = av;
    }
  }
  __syncthreads();

  // ---- Wo-GEMM + per-head LN; wave w = head w; writes combfrag (upper 16KB) ----
  {
    f32x4 acc[4][2];
    #pragma unroll
    for (int mt = 0; mt < 4; ++mt) { acc[mt][0] = (f32x4)0.f; acc[mt][1] = (f32x4)0.f; }
    const bf16x8* pO = reinterpret_cast<const bf16x8*>(ws + OFF_O);
    bf16x8 b0 = pO[(w*2 + 0)*64 + lane];
    bf16x8 b1 = pO[(w*2 + 1)*64 + lane];
    #pragma unroll
    for (int mt = 0; mt < 4; ++mt) {
      bf16x8 a = *reinterpret_cast<const bf16x8*>(&s_regA[((w*4 + mt)*64 + lane)*8]);
      acc[mt][0] = MFMA16(a, b0, acc[mt][0]);
      acc[mt][1] = MFMA16(a, b1, acc[mt][1]);
    }
    float bo0 = s_bo[w*32 + lc],  bo1 = s_bo[w*32 + 16 + lc];
    float lg0 = s_lng[w*32 + lc], lg1 = s_lng[w*32 + 16 + lc];
    float lb0 = s_lnb[w*32 + lc], lb1 = s_lnb[w*32 + 16 + lc];
    #pragma unroll
    for (int mt = 0; mt < 4; ++mt)
      #pragma unroll
      for (int r = 0; r < 4; ++r) {
        float v0 = acc[mt][0][r] + bo0;
        float v1 = acc[mt][1][r] + bo1;
        float s = v0 + v1, sq = v0*v0 + v1*v1;
        s += __shfl_xor(s, 1, 64);  sq += __shfl_xor(sq, 1, 64);
        s += __shfl_xor(s, 2, 64);  sq += __shfl_xor(sq, 2, 64);
        s += __shfl_xor(s, 4, 64);  sq += __shfl_xor(sq, 4, 64);
        s += __shfl_xor(s, 8, 64);  sq += __shfl_xor(sq, 8, 64);
        float mean = s * (1.f/32.f);
        float var  = sq * (1.f/32.f) - mean*mean;
        float rstd = rsqrtf(var + 1e-5f);
        float n0 = (v0 - mean)*rstd*lg0 + lb0;
        float n1 = (v1 - mean)*rstd*lg1 + lb1;
        int rl = lr*4 + r;
        int base = 8192 + ((w*4 + mt)*64)*8;
        // combined col = w*32 + o ; o0 = lc, o1 = 16+lc ; lane'=16*(o>>3)+rl, j=o&7=lane&7
        s_regA[base + (16*(lc >> 3)       + rl)*8 + (lane & 7)] = (bf16)n0;
        s_regA[base + (16*(2 + (lc >> 3)) + rl)*8 + (lane & 7)] = (bf16)n1;
      }
  }
  __syncthreads();

  // ---- GEMM2: out_pre = combined(64x128) * Wf(128x256); wave w -> cols [64w,64w+64) ----
  f32x4 acc2[4][4];
  {
    #pragma unroll
    for (int mt = 0; mt < 4; ++mt)
      #pragma unroll
      for (int nt = 0; nt < 4; ++nt) acc2[mt][nt] = (f32x4)0.f;
    const bf16x8* pF = reinterpret_cast<const bf16x8*>(ws + OFF_F);
    #pragma unroll
    for (int ks = 0; ks < 4; ++ks) {
      bf16x8 a[4], bb[4];
      #pragma unroll
      for (int mt = 0; mt < 4; ++mt)
        a[mt] = *reinterpret_cast<const bf16x8*>(&s_regA[8192 + ((ks*4 + mt)*64 + lane)*8]);
      #pragma unroll
      for (int nt = 0; nt < 4; ++nt)
        bb[nt] = pF[(ks*16 + w*4 + nt)*64 + lane];
      #pragma unroll
      for (int mt = 0; mt < 4; ++mt)
        #pragma unroll
        for (int nt = 0; nt < 4; ++nt)
          acc2[mt][nt] = MFMA16(a[mt], bb[nt], acc2[mt][nt]);
    }
    #pragma unroll
    for (int nt = 0; nt < 4; ++nt) {
      float bfv = s_bf[w*64 + nt*16 + lc];
      #pragma unroll
      for (int mt = 0; mt < 4; ++mt)
        #pragma unroll
        for (int r = 0; r < 4; ++r) acc2[mt][nt][r] += bfv;
    }
  }
  __syncthreads();   // all combfrag reads done before opfrag overwrites region A
  {
    #pragma unroll
    for (int mt = 0; mt < 4; ++mt)
      #pragma unroll
      for (int nt = 0; nt < 4; ++nt) {
        int ks3 = w*2 + (nt >> 1);
        #pragma unroll
        for (int r = 0; r < 4; ++r) {
          int lane2 = 16*((nt & 1)*2 + (lc >> 3)) + (lr*4 + r);
          s_regA[((ks3*4 + mt)*64 + lane2)*8 + (lane & 7)] = (bf16)acc2[mt][nt][r];
        }
      }
  }
  __syncthreads();

  // ---- GEMM3: hidden = relu(out_pre(64x256)*Wg1(256x64) + diff*wg1d + bg1); wave w -> cols [16w,16w+16) ----
  {
    f32x4 acc3[4];
    #pragma unroll
    for (int mt = 0; mt < 4; ++mt) acc3[mt] = (f32x4)0.f;
    const bf16x8* pG1 = reinterpret_cast<const bf16x8*>(ws + OFF_G1);
    #pragma unroll
    for (int ks = 0; ks < 8; ++ks) {
      bf16x8 b = pG1[(ks*4 + w)*64 + lane];
      #pragma unroll
      for (int mt = 0; mt < 4; ++mt) {
        bf16x8 a = *reinterpret_cast<const bf16x8*>(&s_regA[((ks*4 + mt)*64 + lane)*8]);
        acc3[mt] = MFMA16(a, b, acc3[mt]);
      }
    }
    int col3 = w*16 + lc;
    float b1v = s_bg1[col3], wdv = s_wg1d[col3];
    #pragma unroll
    for (int mt = 0; mt < 4; ++mt)
      #pragma unroll
      for (int r = 0; r < 4; ++r) {
        int row = mt*16 + lr*4 + r;
        float hv = acc3[mt][r] + b1v + s_diff[row]*wdv;
        hv = fmaxf(hv, 0.f);
        // hfrag: ks4 = w>>1, lane2 = 16*((w&1)*2 + (lc>>3)) + (row&15), j = lane&7
        s_hfrag[(((w >> 1)*4 + mt)*64 + 16*((w & 1)*2 + (lc >> 3)) + (lr*4 + r))*8 + (lane & 7)] = (bf16)hv;
      }
  }
  __syncthreads();

  // ---- GEMM4: gate = sigmoid(hidden(64x64)*Wg2(64x256)+bg2); val = out_pre*gate + x ----
  {
    f32x4 acc4[4][4];
    #pragma unroll
    for (int mt = 0; mt < 4; ++mt)
      #pragma unroll
      for (int nt = 0; nt < 4; ++nt) acc4[mt][nt] = (f32x4)0.f;
    const bf16x8* pG2 = reinterpret_cast<const bf16x8*>(ws + OFF_G2);
    #pragma unroll
    for (int ks = 0; ks < 2; ++ks) {
      bf16x8 a[4], bb[4];
      #pragma unroll
      for (int mt = 0; mt < 4; ++mt)
        a[mt] = *reinterpret_cast<const bf16x8*>(&s_hfrag[((ks*4 + mt)*64 + lane)*8]);
      #pragma unroll
      for (int nt = 0; nt < 4; ++nt)
        bb[nt] = pG2[(ks*16 + w*4 + nt)*64 + lane];
      #pragma unroll
      for (int mt = 0; mt < 4; ++mt)
        #pragma unroll
        for (int nt = 0; nt < 4; ++nt)
          acc4[mt][nt] = MFMA16(a[mt], bb[nt], acc4[mt][nt]);
    }
    const float* xbase = x + (size_t)row0 * D;
    #pragma unroll
    for (int nt = 0; nt < 4; ++nt) {
      int c = w*64 + nt*16 + lc;
      float bg2v = s_bg2[c];
      #pragma unroll
      for (int mt = 0; mt < 4; ++mt)
        #pragma unroll
        for (int r = 0; r < 4; ++r) {
          int row = mt*16 + lr*4 + r;
          float gate = 1.f / (1.f + expf(-(acc4[mt][nt][r] + bg2v)));
          acc2[mt][nt][r] = acc2[mt][nt][r]*gate + xbase[row*D + c];
        }
    }
  }
  // ---- final LN partials (per row over this wave's 64 cols) ----
  {
    #pragma unroll
    for (int mt = 0; mt < 4; ++mt)
      #pragma unroll
      for (int r = 0; r < 4; ++r) {
        float s = 0.f, sq = 0.f;
        #pragma unroll
        for (int nt = 0; nt < 4; ++nt) {
          float v = acc2[mt][nt][r];
          s += v; sq = fmaf(v, v, sq);
        }
        s += __shfl_xor(s, 1, 64);  sq += __shfl_xor(sq, 1, 64);
        s += __shfl_xor(s, 2, 64);  sq += __shfl_xor(sq, 2, 64);
        s += __shfl_xor(s, 4, 64);  sq += __shfl_xor(sq, 4, 64);
        s += __shfl_xor(s, 8, 64);  sq += __shfl_xor(sq, 8, 64);
        if (lc == 0) {
          int row = mt*16 + lr*4 + r;
          s_lnsum[row*4 + w] = s;
          s_lnsq[row*4 + w]  = sq;
        }
      }
  }
  __syncthreads();
  if (t < ROWS) {
    float s  = s_lnsum[t*4] + s_lnsum[t*4+1] + s_lnsum[t*4+2] + s_lnsum[t*4+3];
    float sq = s_lnsq[t*4]  + s_lnsq[t*4+1]  + s_lnsq[t*4+2]  + s_lnsq[t*4+3];
    float mean = s * (1.f/256.f);
    float var  = sq * (1.f/256.f) - mean*mean;
    s_rmean[t] = mean;
    s_rrstd[t] = rsqrtf(var + 1e-5f);
  }
  __syncthreads();
  {
    float* obase = out + (size_t)row0 * D;
    #pragma unroll
    for (int mt = 0; mt < 4; ++mt)
      #pragma unroll
      for (int r = 0; r < 4; ++r) {
        int row = mt*16 + lr*4 + r;
        float mean = s_rmean[row], rstd = s_rrstd[row];
        #pragma unroll
        for (int nt = 0; nt < 4; ++nt) {
          int c = w*64 + nt*16 + lc;
          obase[row*D + c] = (acc2[mt][nt][r] - mean)*rstd*s_lnFg[c] + s_lnFb[c];
        }
      }
  }
}

extern "C" void kernel_launch(void* const* d_in, const int* in_sizes, int n_in,
                              void* d_out, int out_size, void* d_ws, size_t ws_size,
                              hipStream_t stream) {
  (void)in_sizes; (void)n_in; (void)ws_size; (void)out_size;
  const float* x   = (const float*)d_in[0];
  const float* mp  = (const float*)d_in[1];
  const float* Wq  = (const float*)d_in[2];
  const float* bq  = (const float*)d_in[3];
  const float* pk  = (const float*)d_in[4];
  const float* pv  = (const float*)d_in[5];
  const float* imp = (const float*)d_in[6];
  const float* fa  = (const float*)d_in[7];
  const float* ft  = (const float*)d_in[8];
  const float* Wo  = (const float*)d_in[9];
  const float* bo  = (const float*)d_in[10];
  const float* lng = (const float*)d_in[11];
  const float* lnb = (const float*)d_in[12];
  const float* Wf  = (const float*)d_in[13];
  const float* bf  = (const float*)d_in[14];
  const float* Wg1 = (const float*)d_in[15];
  const float* bg1 = (const float*)d_in[16];
  const float* Wg2 = (const float*)d_in[17];
  const float* bg2 = (const float*)d_in[18];
  const float* lnFg= (const float*)d_in[19];
  const float* lnFb= (const float*)d_in[20];
  float* out = (float*)d_out;
  bf16* ws = (bf16*)d_ws;

  hipLaunchKernelGGL(prep_kernel, dim3((NPACK + 255)/256), dim3(256), 0, stream,
                     Wq, Wf, Wg1, Wg2, Wo, ws);
  hipLaunchKernelGGL(faiia_kernel, dim3(NROWS_TOT / ROWS), dim3(256), 0, stream,
                     x, mp, bq, pk, pv, imp, fa, ft, bo, lng, lnb,
                     bf, Wg1, bg1, bg2, lnFg, lnFb, ws, out);
}